// Round 5
// baseline (136.875 us; speedup 1.0000x reference)
//
#include <hip/hip_runtime.h>

typedef _Float16 half8 __attribute__((ext_vector_type(8)));
typedef float floatx4 __attribute__((ext_vector_type(4)));
typedef int intx4 __attribute__((ext_vector_type(4)));
typedef int intx8 __attribute__((ext_vector_type(8)));

#define SCALE_POS 2.0f
#define SCALE_NEG 40.0f
#define THRESH 0.5f
#define MARGIN 0.1f
#define EPSV 1e-5f

// ---- kernel 1: fp32 -> fp8 e4m3 (OCP, RNE via HW cvt) + out zero ----
__global__ void k_init(const float* __restrict__ feats,
                       unsigned char* __restrict__ f8,
                       float* __restrict__ out,
                       int total4) {
    int i = blockIdx.x * blockDim.x + threadIdx.x;
    if (i < total4) {
        float4 v = ((const float4*)feats)[i];
        int w = 0;
        w = __builtin_amdgcn_cvt_pk_fp8_f32(v.x, v.y, w, false);  // bytes 0,1
        w = __builtin_amdgcn_cvt_pk_fp8_f32(v.z, v.w, w, true);   // bytes 2,3
        ((int*)f8)[i] = w;
    }
    if (i == 0) out[0] = 0.f;
}

// =====================================================================
// kernel 2 (R21): MX-fp8 symmetric GEMM over FULL 128x128 tiles.
// 528 blocks x 256 thr (4 waves, 2x2 grid of 64x64 sub-tiles).
//
// CHANGE vs R20: staging switched from global_load_lds with XOR-
// permuted 16B-granule SOURCE addresses (measured ~5 B/cyc/CU DMA —
// 4x below m97's 22 B/cyc with linear sources; the permuted granule
// order is the prime suspect for coalescing loss) to REG-STAGING:
//   global_load_dwordx4 with LINEAR in-order lane addresses
//   (lane L: row c*8+(L>>3), byte (L&7)*16 — monotonic 128B runs)
//   -> ds_write_b128 to the swizzled LDS slot.
// Physical LDS layout is byte-identical to R20 (block b of row r at
// r*128 + (b^(r&7))*16), so the ds_read/MFMA/epilogue side is
// untouched. ds_writes are bank-conflict-free (each 8-lane group
// covers all 8 bank-quads of its row).
// Pipeline (T14 issue-early/write-late):
//   issue loads(kt+1) -> regs            (in flight under compute)
//   s_waitcnt lgkmcnt(0); s_barrier      (raw: no vmcnt drain!)
//   ds_read + 16 MFMA (tile kt)
//   __syncthreads()                      (vmcnt(0) = wait loads(kt+1),
//                                         already landed; + read-WAR)
//   ds_write regs -> LDS (tile kt+1)
// Stats epilogue: unique-writer partial slots (R20, verified).
// =====================================================================
__global__ void __launch_bounds__(256, 2)
k_gemm_h(const unsigned char* __restrict__ f8,
         const int* __restrict__ labels,
         float* __restrict__ pmin,     // [64][B] partial min-pos
         float* __restrict__ pmax,     // [64][B] partial max-neg
         _Float16* __restrict__ simh,
         int D, int nb) {      // D = 1024 elements = 1024 bytes/row
    // S[0..16K) = A tile, S[16K..32K) = B tile
    __shared__ __align__(16) unsigned char S[32 * 1024];   // 32 KB
    __shared__ int labR[128], labC[128];

    const int Bsz = nb * 128;

    // bijective XCD-aware swizzle: 528 tiles = 8 XCDs x 66
    const int bid0 = blockIdx.x;
    const int t = (bid0 & 7) * 66 + (bid0 >> 3);
    int rb = 0, rem = t;
    while (rem >= nb - rb) { rem -= nb - rb; ++rb; }
    const int cb = rb + rem;
    const int rowBase = rb * 128;
    const int colBase = cb * 128;

    const int tid = threadIdx.x;        // 0..255
    const int lane = tid & 63;
    const int wave = tid >> 6;          // 0..3
    const int wr = wave >> 1;           // row half of output tile
    const int wc = wave & 1;            // col half of output tile
    const int q = lane >> 4;
    const int cIn = lane & 15;

    if (tid < 128) labR[tid] = labels[rowBase + tid];
    else           labC[tid - 128] = labels[colBase + (tid - 128)];

    // staging: 32 chunks of 1KB (8 rows x 128B). Wave handles 8.
    // LINEAR source order: lane L -> row c*8+(L>>3), byte (L&7)*16.
    // LDS write slot: phys block = (L&7) ^ subrow (row-XOR swizzle).
    const int subrow = lane >> 3;            // 0..7
    const int blk = lane & 7;                // logical 16B block
    const unsigned char* gA[8];
    int wOff[8];
#pragma unroll
    for (int j = 0; j < 8; ++j) {
        const int c = wave * 8 + j;          // 0..31
        const int grow = (c < 16) ? (rowBase + c * 8 + subrow)
                                  : (colBase + (c - 16) * 8 + subrow);
        gA[j] = f8 + (size_t)grow * D + blk * 16;
        wOff[j] = c * 1024 + subrow * 128 + ((blk ^ subrow) << 4);
    }

    // fragment LDS offsets: row r, 32B k-group q = logical blocks 2q,2q+1
    // physical p = blk ^ (r&7)   (unchanged from R19/R20)
    int aOff0[4], aOff1[4], bOff0[4], bOff1[4];
#pragma unroll
    for (int i = 0; i < 4; ++i) {
        const int rA = wr * 64 + i * 16 + cIn;
        aOff0[i] = rA * 128 + ((2 * q) ^ (rA & 7)) * 16;
        aOff1[i] = rA * 128 + ((2 * q + 1) ^ (rA & 7)) * 16;
        const int rB = wc * 64 + i * 16 + cIn;
        bOff0[i] = 16384 + rB * 128 + ((2 * q) ^ (rB & 7)) * 16;
        bOff1[i] = 16384 + rB * 128 + ((2 * q + 1) ^ (rB & 7)) * 16;
    }

    floatx4 acc[4][4] = {};
    intx4 rg[8];

#define LOADR(kt)                                                              \
    {                                                                          \
        _Pragma("unroll")                                                      \
        for (int j = 0; j < 8; ++j)                                            \
            rg[j] = *(const intx4*)(gA[j] + ((kt) << 7));                      \
    }

#define DSWRITE()                                                              \
    {                                                                          \
        _Pragma("unroll")                                                      \
        for (int j = 0; j < 8; ++j)                                            \
            *(intx4*)(S + wOff[j]) = rg[j];                                    \
    }

#define COMPUTE()                                                              \
    {                                                                          \
        intx8 a[4], b[4];                                                      \
        _Pragma("unroll")                                                      \
        for (int i = 0; i < 4; ++i) {                                          \
            intx4 lo = *(const intx4*)(S + aOff0[i]);                          \
            intx4 hi = *(const intx4*)(S + aOff1[i]);                          \
            a[i] = __builtin_shufflevector(lo, hi, 0, 1, 2, 3, 4, 5, 6, 7);    \
        }                                                                      \
        _Pragma("unroll")                                                      \
        for (int i = 0; i < 4; ++i) {                                          \
            intx4 lo = *(const intx4*)(S + bOff0[i]);                          \
            intx4 hi = *(const intx4*)(S + bOff1[i]);                          \
            b[i] = __builtin_shufflevector(lo, hi, 0, 1, 2, 3, 4, 5, 6, 7);    \
        }                                                                      \
        _Pragma("unroll")                                                      \
        for (int i = 0; i < 4; ++i)                                            \
            _Pragma("unroll")                                                  \
            for (int j2 = 0; j2 < 4; ++j2)                                     \
                acc[i][j2] = __builtin_amdgcn_mfma_scale_f32_16x16x128_f8f6f4( \
                    a[i], b[j2], acc[i][j2], 0, 0,                             \
                    0, 0x7f7f7f7f, 0, 0x7f7f7f7f);                             \
    }

    const int KT = D >> 7;               // 8 iters of K=128

    // prologue: tile 0 -> regs -> LDS (compiler waits rg before write)
    LOADR(0);
    DSWRITE();

    for (int kt = 0; kt < KT; ++kt) {
        if (kt + 1 < KT) LOADR(kt + 1);           // in flight under compute
        // raw barrier: only lgkmcnt (ds_writes visible); loads NOT drained
        asm volatile("s_waitcnt lgkmcnt(0)" ::: "memory");
        __builtin_amdgcn_sched_barrier(0);
        __builtin_amdgcn_s_barrier();
        COMPUTE();
        if (kt + 1 < KT) {
            __syncthreads();    // all waves done reading; vmcnt(0) = rg ready
            DSWRITE();
        }
    }

#undef LOADR
#undef DSWRITE
#undef COMPUTE

    int rLabv[16];
#pragma unroll
    for (int mi = 0; mi < 4; ++mi)
#pragma unroll
        for (int rr = 0; rr < 4; ++rr)
            rLabv[mi * 4 + rr] = labR[wr * 64 + mi * 16 + q * 4 + rr];
    int cLabv[4];
#pragma unroll
    for (int ni = 0; ni < 4; ++ni)
        cLabv[ni] = labC[wc * 64 + ni * 16 + cIn];

    // ---- fp16 store: identical per-64-col-half layout to R13/R14 ----
    {
        half8* dst = (half8*)(simh + (size_t)(2 * t + wc) * 8192
                                   + (size_t)(wr * 64 + lane) * 64);
#pragma unroll
        for (int mi = 0; mi < 4; ++mi) {
            half8 h0, h1;
#pragma unroll
            for (int ni = 0; ni < 2; ++ni)
#pragma unroll
                for (int rr = 0; rr < 4; ++rr) {
                    h0[ni * 4 + rr] = (_Float16)acc[mi][ni][rr];
                    h1[ni * 4 + rr] = (_Float16)acc[mi][ni + 2][rr];
                }
            dst[mi * 2] = h0;
            dst[mi * 2 + 1] = h1;
        }
    }

    // ---- row stats partials: slot (2*cb+wc), plain stores ----
    {
        float* pmnRow = pmin + (size_t)(2 * cb + wc) * Bsz + rowBase;
        float* pmxRow = pmax + (size_t)(2 * cb + wc) * Bsz + rowBase;
#pragma unroll
        for (int mi = 0; mi < 4; ++mi)
#pragma unroll
            for (int rr = 0; rr < 4; ++rr) {
                const int rLoc = wr * 64 + mi * 16 + q * 4 + rr;
                const int rLab = rLabv[mi * 4 + rr];
                float vmin = 1e30f, vmax = -1e30f;
#pragma unroll
                for (int ni = 0; ni < 4; ++ni) {
                    float s = acc[mi][ni][rr];
                    if (rLab == cLabv[ni]) {
                        if (s < 1.0f - EPSV) vmin = fminf(vmin, s);
                    } else {
                        vmax = fmaxf(vmax, s);
                    }
                }
#pragma unroll
                for (int off = 8; off; off >>= 1) {
                    vmin = fminf(vmin, __shfl_xor(vmin, off, 16));
                    vmax = fmaxf(vmax, __shfl_xor(vmax, off, 16));
                }
                if (cIn == 0) {
                    pmnRow[rLoc] = vmin;
                    pmxRow[rLoc] = vmax;
                }
            }
    }

    // ---- col stats partials via symmetry (off-diag only): slot (2*rb+wr) ----
    if (rb != cb) {
        float* pmnCol = pmin + (size_t)(2 * rb + wr) * Bsz + colBase;
        float* pmxCol = pmax + (size_t)(2 * rb + wr) * Bsz + colBase;
#pragma unroll
        for (int ni = 0; ni < 4; ++ni) {
            const int cLab = cLabv[ni];
            float vmin = 1e30f, vmax = -1e30f;
#pragma unroll
            for (int mi = 0; mi < 4; ++mi)
#pragma unroll
                for (int rr = 0; rr < 4; ++rr) {
                    float s = acc[mi][ni][rr];
                    if (rLabv[mi * 4 + rr] == cLab) {
                        if (s < 1.0f - EPSV) vmin = fminf(vmin, s);
                    } else {
                        vmax = fmaxf(vmax, s);
                    }
                }
            vmin = fminf(vmin, __shfl_xor(vmin, 16, 64));
            vmin = fminf(vmin, __shfl_xor(vmin, 32, 64));
            vmax = fmaxf(vmax, __shfl_xor(vmax, 16, 64));
            vmax = fmaxf(vmax, __shfl_xor(vmax, 32, 64));
            if (q == 0) {
                const int cLoc = wc * 64 + ni * 16 + cIn;
                pmnCol[cLoc] = vmin;
                pmxCol[cLoc] = vmax;
            }
        }
    }
}

// =====================================================================
// kernel 2.5: reduce stat partials -> gate arrays (pre-offset by MARGIN)
// =====================================================================
__global__ void __launch_bounds__(256)
k_stats(const float* __restrict__ pmin, const float* __restrict__ pmax,
        float* __restrict__ gateN, float* __restrict__ gateP, int B) {
    const int r = blockIdx.x * 256 + threadIdx.x;
    float mn = 1e30f, mx = -1e30f;
    for (int k = 0; k < 64; ++k) {
        mn = fminf(mn, pmin[(size_t)k * B + r]);
        mx = fmaxf(mx, pmax[(size_t)k * B + r]);
    }
    gateN[r] = mn - MARGIN;
    gateP[r] = mx + MARGIN;
}

// =====================================================================
// kernel 3 (R20, verified): pass 2, gated exp sums -> unique-writer
// partial arrays psP/psN [64][B]. No atomics.
// =====================================================================
__global__ void __launch_bounds__(256)
k_sum2f(const _Float16* __restrict__ simh,
        const int* __restrict__ labels,
        const float* __restrict__ gateN,
        const float* __restrict__ gateP,
        float* __restrict__ psP, float* __restrict__ psN,
        int nb, int B) {
    __shared__ int labR[128], labC[128];
    __shared__ float gNR[128], gPR[128], gNC[128], gPC[128];

    int t = blockIdx.x;
    int rb = 0, rem = t;
    while (rem >= nb - rb) { rem -= nb - rb; ++rb; }
    const int cb = rb + rem;
    const int rowBase = rb * 128;

    const int tid = threadIdx.x;
    const int sub = tid >> 7;           // 0..1 : col half
    const int stid = tid & 127;
    const int wave = stid >> 6;         // 0..1 : row half within sub
    const int lane = tid & 63;
    const int q = lane >> 4;
    const int cIn = lane & 15;
    const int colBase = cb * 128 + sub * 64;

    if (tid < 128) {
        labR[tid] = labels[rowBase + tid];
        gNR[tid] = gateN[rowBase + tid];
        gPR[tid] = gateP[rowBase + tid];
    } else {
        const int j = tid - 128;
        labC[j] = labels[cb * 128 + j];
        gNC[j] = gateN[cb * 128 + j];
        gPC[j] = gateP[cb * 128 + j];
    }
    __syncthreads();

    int cLabv[4];
    float gNCv[4], gPCv[4];
#pragma unroll
    for (int ni = 0; ni < 4; ++ni) {
        const int j = sub * 64 + ni * 16 + cIn;
        cLabv[ni] = labC[j];
        gNCv[ni] = gNC[j];
        gPCv[ni] = gPC[j];
    }

    const half8* src = (const half8*)(simh + (size_t)(2 * t + sub) * 8192 + (size_t)stid * 64);
    half8 hv[8];
#pragma unroll
    for (int v = 0; v < 8; ++v) hv[v] = src[v];

    float cps[4] = {}, cns[4] = {};
    const bool offd = (rb != cb);

    float* psPRow = psP + (size_t)(2 * cb + sub) * B + rowBase;
    float* psNRow = psN + (size_t)(2 * cb + sub) * B + rowBase;

#pragma unroll
    for (int mi = 0; mi < 4; ++mi)
#pragma unroll
        for (int rr = 0; rr < 4; ++rr) {
            const int rLoc = wave * 64 + mi * 16 + q * 4 + rr;
            const int rLab = labR[rLoc];
            const float gn = gNR[rLoc];
            const float gp = gPR[rLoc];
            float rp = 0.f, rn = 0.f;
#pragma unroll
            for (int ni = 0; ni < 4; ++ni) {
                const int idx = mi * 16 + ni * 4 + rr;
                const float s = (float)hv[idx >> 3][idx & 7];
                if (rLab == cLabv[ni]) {
                    if (s < 1.0f - EPSV) {
                        float ev = __expf(-SCALE_POS * (s - THRESH));
                        if (s < gp) rp += ev;
                        if (offd && s < gPCv[ni]) cps[ni] += ev;
                    }
                } else {
                    float ev = __expf(SCALE_NEG * (s - THRESH));
                    if (s > gn) rn += ev;
                    if (offd && s > gNCv[ni]) cns[ni] += ev;
                }
            }
#pragma unroll
            for (int off = 8; off; off >>= 1) {
                rp += __shfl_xor(rp, off, 16);
                rn += __shfl_xor(rn, off, 16);
            }
            if (cIn == 0) {
                psPRow[rLoc] = rp;      // unique slot, plain store
                psNRow[rLoc] = rn;
            }
        }
    if (offd) {
        float* psPCol = psP + (size_t)(2 * rb + wave) * B + colBase;
        float* psNCol = psN + (size_t)(2 * rb + wave) * B + colBase;
#pragma unroll
        for (int ni = 0; ni < 4; ++ni) {
            cps[ni] += __shfl_xor(cps[ni], 16, 64);
            cps[ni] += __shfl_xor(cps[ni], 32, 64);
            cns[ni] += __shfl_xor(cns[ni], 16, 64);
            cns[ni] += __shfl_xor(cns[ni], 32, 64);
            if (q == 0) {
                const int cLoc = ni * 16 + cIn;
                psPCol[cLoc] = cps[ni];
                psNCol[cLoc] = cns[ni];
            }
        }
    }
}

// =====================================================================
// kernel 4: final reduce -> out[0] (16 blocks, one atomicAdd each)
// =====================================================================
__global__ void __launch_bounds__(256)
k_final(const float* __restrict__ psP, const float* __restrict__ psN,
        float* __restrict__ out, int B) {
    __shared__ float red[4];
    const int r = blockIdx.x * 256 + threadIdx.x;
    float P = 0.f, N = 0.f;
    for (int k = 0; k < 64; ++k) {
        P += psP[(size_t)k * B + r];
        N += psN[(size_t)k * B + r];
    }
    float a = (P > 0.f && N > 0.f)
                  ? log1pf(P) * (1.0f / SCALE_POS) + log1pf(N) * (1.0f / SCALE_NEG)
                  : 0.f;
#pragma unroll
    for (int off = 32; off; off >>= 1) a += __shfl_down(a, off, 64);
    const int tid = threadIdx.x;
    if ((tid & 63) == 0) red[tid >> 6] = a;
    __syncthreads();
    if (tid == 0)
        atomicAdd(out, (red[0] + red[1] + red[2] + red[3]) / (float)B);
}

extern "C" void kernel_launch(void* const* d_in, const int* in_sizes, int n_in,
                              void* d_out, int out_size, void* d_ws, size_t ws_size,
                              hipStream_t stream) {
    const float* feats = (const float*)d_in[0];
    const int* labels = (const int*)d_in[1];
    const int B = in_sizes[1];            // 4096
    const int D = in_sizes[0] / B;        // 1024
    const int nb = B / 128;               // 32
    const int NT = nb * (nb + 1) / 2;     // 528
    const int total4 = B * D / 4;

    char* ws = (char*)d_ws;
    unsigned char* f8 = (unsigned char*)ws;
    size_t off = (size_t)B * D;           // 4 MB fp8
    float* pmin = (float*)(ws + off); off += (size_t)64 * B * 4;   // 1 MB
    float* pmax = (float*)(ws + off); off += (size_t)64 * B * 4;   // 1 MB
    float* psP  = (float*)(ws + off); off += (size_t)64 * B * 4;   // 1 MB
    float* psN  = (float*)(ws + off); off += (size_t)64 * B * 4;   // 1 MB
    float* gateN = (float*)(ws + off); off += (size_t)B * 4;
    float* gateP = (float*)(ws + off); off += (size_t)B * 4;
    _Float16* simh = (_Float16*)(ws + ((off + 255) & ~(size_t)255));
    float* outp = (float*)d_out;

    k_init<<<(total4 + 255) / 256, 256, 0, stream>>>(feats, f8, outp, total4);

    // 528 blocks x 256 thr — full-tile MX-fp8 GEMM, reg-staged linear loads (R21)
    k_gemm_h<<<NT, 256, 0, stream>>>(f8, labels, pmin, pmax, simh, D, nb);

    // gate reduce: 16 blocks
    k_stats<<<B / 256, 256, 0, stream>>>(pmin, pmax, gateN, gateP, B);

    // pass 2: 528 blocks x 256 thr, partial-slot sums
    k_sum2f<<<NT, 256, 0, stream>>>(simh, labels, gateN, gateP, psP, psN, nb, B);

    // final: 16 blocks, one atomic each
    k_final<<<B / 256, 256, 0, stream>>>(psP, psN, outp, B);
}